// Round 1
// baseline (1444.327 us; speedup 1.0000x reference)
//
#include <hip/hip_runtime.h>

constexpr int D = 128;

__device__ __forceinline__ void atomAddF(float* p, float v) {
#if defined(__HIP_PLATFORM_AMD__) || defined(__AMDGCN__)
    unsafeAtomicAdd(p, v);   // HW global_atomic_add_f32 (plain atomicAdd may CAS-loop)
#else
    atomicAdd(p, v);
#endif
}

// deg[c] += 1 for each edge target
__global__ __launch_bounds__(256) void k_deg(const int* __restrict__ col,
                                             int* __restrict__ deg, int E) {
    int i = blockIdx.x * 256 + threadIdx.x;
    if (i < E) atomicAdd(&deg[col[i]], 1);
}

// dinv[i] = rsqrt(deg[i] + 1)   (+1 = self-loop, so always > 0)
__global__ __launch_bounds__(256) void k_dinv(const int* __restrict__ deg,
                                              float* __restrict__ dinv, int n) {
    int i = blockIdx.x * 256 + threadIdx.x;
    if (i < n) dinv[i] = rsqrtf((float)(deg[i] + 1));
}

// y[i][:]  = (seq[i] @ W) * dinv[i]
// out[i][:] = y[i][:] * dinv[i]          (self-loop contribution, initializes d_out)
__global__ __launch_bounds__(256) void k_gemm(const float* __restrict__ seq,
                                              const float* __restrict__ W,
                                              const float* __restrict__ dinv,
                                              float* __restrict__ y,
                                              float* __restrict__ out, int n) {
    __shared__ float sW[64 * D];   // 32 KB: one 64-row k-chunk of W
    __shared__ float sS[16 * D];   // 8 KB: 16 seq rows

    int row0 = blockIdx.x * 16;
    int rows = n - row0; if (rows > 16) rows = 16;

    // stage seq tile (vectorized, coalesced)
    {
        const float4* src = (const float4*)(seq + (size_t)row0 * D);
        float4* dst = (float4*)sS;
        int nf4 = rows * (D / 4);
        for (int i = threadIdx.x; i < nf4; i += 256) dst[i] = src[i];
    }

    int d  = threadIdx.x & 127;   // output column
    int rr = threadIdx.x >> 7;    // 0..1, row parity
    float acc[8] = {0.f, 0.f, 0.f, 0.f, 0.f, 0.f, 0.f, 0.f};

    for (int kc = 0; kc < 2; ++kc) {
        __syncthreads();          // previous sW use done
        {
            const float4* src = (const float4*)(W + (size_t)kc * 64 * D);
            float4* dst = (float4*)sW;
            for (int i = threadIdx.x; i < 64 * D / 4; i += 256) dst[i] = src[i];
        }
        __syncthreads();
        int kbase = kc * 64;
        #pragma unroll 4
        for (int k2 = 0; k2 < 64; ++k2) {
            float w = sW[k2 * D + d];               // 2-way bank alias: free
            int k = kbase + k2;
            #pragma unroll
            for (int j = 0; j < 8; ++j)
                acc[j] += sS[(rr + 2 * j) * D + k] * w;   // broadcast read: free
        }
    }

    #pragma unroll
    for (int j = 0; j < 8; ++j) {
        int r = rr + 2 * j;
        int g = row0 + r;
        if (g < n) {
            float di = dinv[g];
            float v = acc[j] * di;
            y[(size_t)g * D + d]   = v;
            out[(size_t)g * D + d] = v * di;
        }
    }
}

// out[col[e]][:] += y[row[e]][:] * dinv[col[e]]   — 32 threads/edge, float4 each
__global__ __launch_bounds__(256) void k_scatter(const int* __restrict__ row,
                                                 const int* __restrict__ col,
                                                 const float* __restrict__ dinv,
                                                 const float* __restrict__ y,
                                                 float* __restrict__ out, int E) {
    unsigned t = blockIdx.x * 256u + threadIdx.x;
    unsigned e = t >> 5;
    if (e >= (unsigned)E) return;
    int r = row[e];
    int c = col[e];
    float nc = dinv[c];
    int d4 = (int)(t & 31u) << 2;
    float4 v = *(const float4*)(y + (size_t)r * D + d4);
    float* o = out + (size_t)c * D + d4;
    atomAddF(o + 0, v.x * nc);
    atomAddF(o + 1, v.y * nc);
    atomAddF(o + 2, v.z * nc);
    atomAddF(o + 3, v.w * nc);
}

// out = PReLU(out + b)
__global__ __launch_bounds__(256) void k_final(float* __restrict__ out,
                                               const float* __restrict__ b,
                                               const float* __restrict__ pw, int n4) {
    int i = blockIdx.x * 256 + threadIdx.x;
    if (i >= n4) return;
    float4 v = ((float4*)out)[i];
    int d4 = (i & 31) << 2;           // 128/4 = 32 float4 per row
    const float4 bb = *(const float4*)(b + d4);
    float p = pw[0];
    v.x += bb.x; v.y += bb.y; v.z += bb.z; v.w += bb.w;
    v.x = v.x > 0.f ? v.x : p * v.x;
    v.y = v.y > 0.f ? v.y : p * v.y;
    v.z = v.z > 0.f ? v.z : p * v.z;
    v.w = v.w > 0.f ? v.w : p * v.w;
    ((float4*)out)[i] = v;
}

extern "C" void kernel_launch(void* const* d_in, const int* in_sizes, int n_in,
                              void* d_out, int out_size, void* d_ws, size_t ws_size,
                              hipStream_t stream) {
    const float* seq = (const float*)d_in[0];
    const int*   ei  = (const int*)d_in[1];   // [2, E] row-major: row=ei, col=ei+E
    const float* W   = (const float*)d_in[2];
    const float* b   = (const float*)d_in[3];
    const float* pw  = (const float*)d_in[4];
    int n = in_sizes[0] / D;
    int E = in_sizes[1] / 2;

    float* out  = (float*)d_out;
    float* y    = (float*)d_ws;                                   // n*D floats
    int*   deg  = (int*)((char*)d_ws + (size_t)n * D * sizeof(float));
    float* dinv = (float*)(deg + n);

    hipMemsetAsync(deg, 0, (size_t)n * sizeof(int), stream);
    k_deg<<<(E + 255) / 256, 256, 0, stream>>>(ei + E, deg, E);
    k_dinv<<<(n + 255) / 256, 256, 0, stream>>>(deg, dinv, n);
    k_gemm<<<(n + 15) / 16, 256, 0, stream>>>(seq, W, dinv, y, out, n);
    long long tw = (long long)E * 32;
    k_scatter<<<(unsigned)((tw + 255) / 256), 256, 0, stream>>>(ei, ei + E, dinv, y, out, E);
    k_final<<<(n * (D / 4) + 255) / 256, 256, 0, stream>>>(out, b, pw, n * (D / 4));
}

// Round 2
// 213.636 us; speedup vs baseline: 6.7607x; 6.7607x over previous
//
#include <hip/hip_runtime.h>

constexpr int D = 128;

// ---------------- degree histogram of edge targets ----------------
__global__ __launch_bounds__(256) void k_deg(const int* __restrict__ col,
                                             int* __restrict__ deg, int E) {
    int i = blockIdx.x * 256 + threadIdx.x;
    if (i < E) atomicAdd(&deg[col[i]], 1);
}

// ---------------- scan step 1: per-block (1024 elems) exclusive scan ----------------
__global__ __launch_bounds__(256) void k_scan1(const int* __restrict__ deg,
                                               int* __restrict__ start,
                                               int* __restrict__ bsum, int n) {
    int tid = threadIdx.x;
    int lane = tid & 63, wv = tid >> 6;
    int i0 = (blockIdx.x * 256 + tid) * 4;
    int4 v = {0, 0, 0, 0};
    if (i0 + 3 < n) {
        v = *(const int4*)(deg + i0);
    } else {
        if (i0 < n)     v.x = deg[i0];
        if (i0 + 1 < n) v.y = deg[i0 + 1];
        if (i0 + 2 < n) v.z = deg[i0 + 2];
        if (i0 + 3 < n) v.w = deg[i0 + 3];
    }
    int tsum = v.x + v.y + v.z + v.w;
    int x = tsum;
    #pragma unroll
    for (int off = 1; off < 64; off <<= 1) {
        int t = __shfl_up(x, off);
        if (lane >= off) x += t;
    }
    __shared__ int ws[4];
    if (lane == 63) ws[wv] = x;
    __syncthreads();
    int woff = 0;
    #pragma unroll
    for (int w = 0; w < 3; ++w) if (w < wv) woff += ws[w];
    int ex = woff + x - tsum;   // block-local exclusive prefix
    if (i0 < n)     start[i0]     = ex;
    if (i0 + 1 < n) start[i0 + 1] = ex + v.x;
    if (i0 + 2 < n) start[i0 + 2] = ex + v.x + v.y;
    if (i0 + 3 < n) start[i0 + 3] = ex + v.x + v.y + v.z;
    if (tid == 255) bsum[blockIdx.x] = woff + x;   // block total
}

// ---------------- scan step 2: exclusive scan of <=64 block sums ----------------
__global__ __launch_bounds__(64) void k_scan2(int* __restrict__ bsum, int nb) {
    int lane = threadIdx.x;
    int v = (lane < nb) ? bsum[lane] : 0;
    int x = v;
    #pragma unroll
    for (int off = 1; off < 64; off <<= 1) {
        int t = __shfl_up(x, off);
        if (lane >= off) x += t;
    }
    if (lane < nb) bsum[lane] = x - v;   // exclusive
}

// ---------------- scan step 3: add block offsets; init cursor & dinv ----------------
__global__ __launch_bounds__(256) void k_scan3(int* __restrict__ start,
                                               const int* __restrict__ bsum,
                                               int* __restrict__ cursor,
                                               const int* __restrict__ deg,
                                               float* __restrict__ dinv, int n) {
    int i = blockIdx.x * 256 + threadIdx.x;
    if (i >= n) return;
    int s = start[i] + bsum[i >> 10];
    start[i] = s;
    cursor[i] = s;
    dinv[i] = rsqrtf((float)(deg[i] + 1));   // +1 self-loop
}

// ---------------- counting-sort edge sources by target ----------------
__global__ __launch_bounds__(256) void k_sortedges(const int* __restrict__ row,
                                                   const int* __restrict__ col,
                                                   int* __restrict__ cursor,
                                                   int* __restrict__ srow, int E) {
    int i = blockIdx.x * 256 + threadIdx.x;
    if (i < E) {
        int c = col[i];
        int p = atomicAdd(&cursor[c], 1);
        srow[p] = row[i];
    }
}

// ---------------- y[i][:] = (seq[i] @ W) * dinv[i] ----------------
__global__ __launch_bounds__(256) void k_gemm(const float* __restrict__ seq,
                                              const float* __restrict__ W,
                                              const float* __restrict__ dinv,
                                              float* __restrict__ y, int n) {
    __shared__ float sW[64 * D];   // 32 KB: one 64-row k-chunk of W
    __shared__ float sS[16 * D];   // 8 KB: 16 seq rows

    int row0 = blockIdx.x * 16;
    int rows = n - row0; if (rows > 16) rows = 16;

    {
        const float4* src = (const float4*)(seq + (size_t)row0 * D);
        float4* dst = (float4*)sS;
        int nf4 = rows * (D / 4);
        for (int i = threadIdx.x; i < nf4; i += 256) dst[i] = src[i];
    }

    int d  = threadIdx.x & 127;
    int rr = threadIdx.x >> 7;
    float acc[8] = {0.f, 0.f, 0.f, 0.f, 0.f, 0.f, 0.f, 0.f};

    for (int kc = 0; kc < 2; ++kc) {
        __syncthreads();
        {
            const float4* src = (const float4*)(W + (size_t)kc * 64 * D);
            float4* dst = (float4*)sW;
            for (int i = threadIdx.x; i < 64 * D / 4; i += 256) dst[i] = src[i];
        }
        __syncthreads();
        int kbase = kc * 64;
        #pragma unroll 4
        for (int k2 = 0; k2 < 64; ++k2) {
            float w = sW[k2 * D + d];
            int k = kbase + k2;
            #pragma unroll
            for (int j = 0; j < 8; ++j)
                acc[j] += sS[(rr + 2 * j) * D + k] * w;
        }
    }

    #pragma unroll
    for (int j = 0; j < 8; ++j) {
        int r = rr + 2 * j;
        int g = row0 + r;
        if (g < n) y[(size_t)g * D + d] = acc[j] * dinv[g];
    }
}

// ---------------- per-node gather-reduce + bias + PReLU ----------------
// out[c] = prelu( dinv[c] * ( y[c] + sum_{e: col=c} y[srow[e]] ) + b )
__global__ __launch_bounds__(256) void k_agg(const int* __restrict__ srow,
                                             const int* __restrict__ start,
                                             const int* __restrict__ deg,
                                             const float* __restrict__ y,
                                             const float* __restrict__ dinv,
                                             const float* __restrict__ b,
                                             const float* __restrict__ pw,
                                             float* __restrict__ out, int n) {
    int wid = (blockIdx.x * 256 + threadIdx.x) >> 6;   // one wave per node
    if (wid >= n) return;
    int lane = threadIdx.x & 63;

    int s = start[wid];
    int cnt = deg[wid];

    // self-loop term: y[wid] (norm dinv[c] applied at the end)
    float2 acc = *(const float2*)(y + (size_t)wid * D + 2 * lane);

    for (int base = 0; base < cnt; base += 64) {
        int chunk = cnt - base; if (chunk > 64) chunk = 64;
        int my = (base + lane < cnt) ? srow[s + base + lane] : 0;
        for (int k = 0; k < chunk; ++k) {
            int r = __shfl(my, k);
            float2 v = *(const float2*)(y + (size_t)r * D + 2 * lane);
            acc.x += v.x;
            acc.y += v.y;
        }
    }

    float di = dinv[wid];
    float2 bb = *(const float2*)(b + 2 * lane);
    float p = pw[0];
    float vx = acc.x * di + bb.x;
    float vy = acc.y * di + bb.y;
    vx = vx > 0.f ? vx : p * vx;
    vy = vy > 0.f ? vy : p * vy;
    *(float2*)(out + (size_t)wid * D + 2 * lane) = make_float2(vx, vy);
}

extern "C" void kernel_launch(void* const* d_in, const int* in_sizes, int n_in,
                              void* d_out, int out_size, void* d_ws, size_t ws_size,
                              hipStream_t stream) {
    const float* seq = (const float*)d_in[0];
    const int*   ei  = (const int*)d_in[1];   // [2, E]: row = ei, col = ei + E
    const float* W   = (const float*)d_in[2];
    const float* b   = (const float*)d_in[3];
    const float* pw  = (const float*)d_in[4];
    int n = in_sizes[0] / D;
    int E = in_sizes[1] / 2;

    float* out = (float*)d_out;

    // workspace layout (256B-aligned chunks)
    auto align = [](size_t x) { return (x + 255) & ~(size_t)255; };
    char* p = (char*)d_ws;
    float* y    = (float*)p;  p += align((size_t)n * D * sizeof(float));
    int*   deg  = (int*)p;    p += align((size_t)n * sizeof(int));
    float* dinv = (float*)p;  p += align((size_t)n * sizeof(float));
    int*   strt = (int*)p;    p += align((size_t)n * sizeof(int));
    int*   curs = (int*)p;    p += align((size_t)n * sizeof(int));
    int*   bsum = (int*)p;    p += align(64 * sizeof(int));
    int*   srow = (int*)p;    p += align((size_t)E * sizeof(int));

    int nb = (n + 1023) / 1024;   // blocks in scan1 (<= 64 supported by scan2)

    hipMemsetAsync(deg, 0, (size_t)n * sizeof(int), stream);
    k_deg<<<(E + 255) / 256, 256, 0, stream>>>(ei + E, deg, E);
    k_scan1<<<nb, 256, 0, stream>>>(deg, strt, bsum, n);
    k_scan2<<<1, 64, 0, stream>>>(bsum, nb);
    k_scan3<<<(n + 255) / 256, 256, 0, stream>>>(strt, bsum, curs, deg, dinv, n);
    k_sortedges<<<(E + 255) / 256, 256, 0, stream>>>(ei, ei + E, curs, srow, E);
    k_gemm<<<(n + 15) / 16, 256, 0, stream>>>(seq, W, dinv, y, n);
    long long waves = (long long)n;
    k_agg<<<(unsigned)((waves * 64 + 255) / 256), 256, 0, stream>>>(
        srow, strt, deg, y, dinv, b, pw, out, n);
}

// Round 3
// 178.157 us; speedup vs baseline: 8.1071x; 1.1991x over previous
//
#include <hip/hip_runtime.h>

constexpr int D = 128;

// ---------------- degree histogram of edge targets ----------------
__global__ __launch_bounds__(256) void k_deg(const int* __restrict__ col,
                                             int* __restrict__ deg, int E) {
    int i = blockIdx.x * 256 + threadIdx.x;
    if (i < E) atomicAdd(&deg[col[i]], 1);
}

// ---------------- scan step 1: per-block (1024 elems) exclusive scan ----------------
__global__ __launch_bounds__(256) void k_scan1(const int* __restrict__ deg,
                                               int* __restrict__ start,
                                               int* __restrict__ bsum, int n) {
    int tid = threadIdx.x;
    int lane = tid & 63, wv = tid >> 6;
    int i0 = (blockIdx.x * 256 + tid) * 4;
    int4 v = {0, 0, 0, 0};
    if (i0 + 3 < n) {
        v = *(const int4*)(deg + i0);
    } else {
        if (i0 < n)     v.x = deg[i0];
        if (i0 + 1 < n) v.y = deg[i0 + 1];
        if (i0 + 2 < n) v.z = deg[i0 + 2];
        if (i0 + 3 < n) v.w = deg[i0 + 3];
    }
    int tsum = v.x + v.y + v.z + v.w;
    int x = tsum;
    #pragma unroll
    for (int off = 1; off < 64; off <<= 1) {
        int t = __shfl_up(x, off);
        if (lane >= off) x += t;
    }
    __shared__ int ws[4];
    if (lane == 63) ws[wv] = x;
    __syncthreads();
    int woff = 0;
    #pragma unroll
    for (int w = 0; w < 3; ++w) if (w < wv) woff += ws[w];
    int ex = woff + x - tsum;   // block-local exclusive prefix
    if (i0 < n)     start[i0]     = ex;
    if (i0 + 1 < n) start[i0 + 1] = ex + v.x;
    if (i0 + 2 < n) start[i0 + 2] = ex + v.x + v.y;
    if (i0 + 3 < n) start[i0 + 3] = ex + v.x + v.y + v.z;
    if (tid == 255) bsum[blockIdx.x] = woff + x;   // block total
}

// ---------------- scan step 2: exclusive scan of <=64 block sums ----------------
__global__ __launch_bounds__(64) void k_scan2(int* __restrict__ bsum, int nb) {
    int lane = threadIdx.x;
    int v = (lane < nb) ? bsum[lane] : 0;
    int x = v;
    #pragma unroll
    for (int off = 1; off < 64; off <<= 1) {
        int t = __shfl_up(x, off);
        if (lane >= off) x += t;
    }
    if (lane < nb) bsum[lane] = x - v;   // exclusive
}

// ---------------- scan step 3: add block offsets; init cursor & dinv ----------------
__global__ __launch_bounds__(256) void k_scan3(int* __restrict__ start,
                                               const int* __restrict__ bsum,
                                               int* __restrict__ cursor,
                                               const int* __restrict__ deg,
                                               float* __restrict__ dinv, int n) {
    int i = blockIdx.x * 256 + threadIdx.x;
    if (i >= n) return;
    int s = start[i] + bsum[i >> 10];
    start[i] = s;
    cursor[i] = s;
    dinv[i] = rsqrtf((float)(deg[i] + 1));   // +1 self-loop
}

// ---------------- hybrid: edge placement (counting sort) || GEMM ----------------
// blocks [0, placeBlocks):       srow[cursor[col[e]]++] = row[e]   (grid-stride)
// blocks [placeBlocks, +gemmB):  y[i][:] = (seq[i] @ W) * dinv[i]  (32-row tiles)
__global__ __launch_bounds__(256) void k_place_gemm(
        const int* __restrict__ row, const int* __restrict__ col,
        int* __restrict__ cursor, int* __restrict__ srow, int E, int placeBlocks,
        const float* __restrict__ seq, const float* __restrict__ W,
        const float* __restrict__ dinv, float* __restrict__ y, int n) {
    __shared__ float sW[64 * D];   // 32 KB: one 64-k-row chunk of W
    __shared__ float sS[32 * D];   // 16 KB: 32 seq rows

    if ((int)blockIdx.x < placeBlocks) {
        int stride = placeBlocks * 256;
        int i = blockIdx.x * 256 + threadIdx.x;
        // 4-wide unroll: independent atomics + scattered stores in flight
        for (; i + 3 * stride < E; i += 4 * stride) {
            int c0 = col[i];
            int c1 = col[i + stride];
            int c2 = col[i + 2 * stride];
            int c3 = col[i + 3 * stride];
            int r0 = row[i];
            int r1 = row[i + stride];
            int r2 = row[i + 2 * stride];
            int r3 = row[i + 3 * stride];
            int p0 = atomicAdd(&cursor[c0], 1);
            int p1 = atomicAdd(&cursor[c1], 1);
            int p2 = atomicAdd(&cursor[c2], 1);
            int p3 = atomicAdd(&cursor[c3], 1);
            srow[p0] = r0; srow[p1] = r1; srow[p2] = r2; srow[p3] = r3;
        }
        for (; i < E; i += stride) {
            int p = atomicAdd(&cursor[col[i]], 1);
            srow[p] = row[i];
        }
        return;
    }

    // ---- GEMM path ----
    int bid = (int)blockIdx.x - placeBlocks;
    int row0 = bid * 32;
    int rows = n - row0; if (rows > 32) rows = 32;

    {   // stage seq tile
        const float4* src = (const float4*)(seq + (size_t)row0 * D);
        float4* dst = (float4*)sS;
        int nf4 = rows * (D / 4);
        for (int i = threadIdx.x; i < nf4; i += 256) dst[i] = src[i];
    }

    int cg = threadIdx.x & 31;    // col quad: d = cg*4 .. cg*4+3
    int rg = threadIdx.x >> 5;    // row group: rows rg*4 .. rg*4+3
    float4 acc[4];
    #pragma unroll
    for (int j = 0; j < 4; ++j) acc[j] = make_float4(0.f, 0.f, 0.f, 0.f);

    for (int kc = 0; kc < 2; ++kc) {
        __syncthreads();
        {
            const float4* src = (const float4*)(W + (size_t)kc * 64 * D);
            float4* dst = (float4*)sW;
            #pragma unroll
            for (int t = 0; t < 8; ++t) dst[threadIdx.x + 256 * t] = src[threadIdx.x + 256 * t];
        }
        __syncthreads();
        int kbase = kc * 64;
        #pragma unroll 4
        for (int k2 = 0; k2 < 64; ++k2) {
            float4 w = *(const float4*)(sW + k2 * D + cg * 4);
            int k = kbase + k2;
            #pragma unroll
            for (int j = 0; j < 4; ++j) {
                float s = sS[(rg * 4 + j) * D + k];   // 2 addrs/wave: broadcast, free
                acc[j].x += s * w.x;
                acc[j].y += s * w.y;
                acc[j].z += s * w.z;
                acc[j].w += s * w.w;
            }
        }
    }

    #pragma unroll
    for (int j = 0; j < 4; ++j) {
        int g = row0 + rg * 4 + j;
        if (g < n) {
            float di = dinv[g];
            float4 v = acc[j];
            v.x *= di; v.y *= di; v.z *= di; v.w *= di;
            *(float4*)(y + (size_t)g * D + cg * 4) = v;
        }
    }
}

// ---------------- per-node gather-reduce + bias + PReLU ----------------
// out[c] = prelu( dinv[c] * ( y[c] + sum_{e: col=c} y[srow[e]] ) + b )
__global__ __launch_bounds__(256) void k_agg(const int* __restrict__ srow,
                                             const int* __restrict__ start,
                                             const int* __restrict__ deg,
                                             const float* __restrict__ y,
                                             const float* __restrict__ dinv,
                                             const float* __restrict__ b,
                                             const float* __restrict__ pw,
                                             float* __restrict__ out, int n) {
    int wid = (blockIdx.x * 256 + threadIdx.x) >> 6;   // one wave per node
    if (wid >= n) return;
    int lane = threadIdx.x & 63;

    int s = start[wid];
    int cnt = deg[wid];

    // self-loop term
    float2 self = *(const float2*)(y + (size_t)wid * D + 2 * lane);
    float ax0 = self.x, ay0 = self.y;
    float ax1 = 0.f, ay1 = 0.f, ax2 = 0.f, ay2 = 0.f, ax3 = 0.f, ay3 = 0.f;

    for (int base = 0; base < cnt; base += 64) {
        int chunk = cnt - base; if (chunk > 64) chunk = 64;
        int my = (base + lane < cnt) ? srow[s + base + lane] : 0;
        int k = 0;
        for (; k + 3 < chunk; k += 4) {   // 4 independent gathers in flight
            int r0 = __shfl(my, k);
            int r1 = __shfl(my, k + 1);
            int r2 = __shfl(my, k + 2);
            int r3 = __shfl(my, k + 3);
            float2 v0 = *(const float2*)(y + (size_t)r0 * D + 2 * lane);
            float2 v1 = *(const float2*)(y + (size_t)r1 * D + 2 * lane);
            float2 v2 = *(const float2*)(y + (size_t)r2 * D + 2 * lane);
            float2 v3 = *(const float2*)(y + (size_t)r3 * D + 2 * lane);
            ax0 += v0.x; ay0 += v0.y;
            ax1 += v1.x; ay1 += v1.y;
            ax2 += v2.x; ay2 += v2.y;
            ax3 += v3.x; ay3 += v3.y;
        }
        for (; k < chunk; ++k) {
            int r = __shfl(my, k);
            float2 v = *(const float2*)(y + (size_t)r * D + 2 * lane);
            ax0 += v.x; ay0 += v.y;
        }
    }

    float sx = (ax0 + ax1) + (ax2 + ax3);
    float sy = (ay0 + ay1) + (ay2 + ay3);

    float di = dinv[wid];
    float2 bb = *(const float2*)(b + 2 * lane);
    float p = pw[0];
    float vx = sx * di + bb.x;
    float vy = sy * di + bb.y;
    vx = vx > 0.f ? vx : p * vx;
    vy = vy > 0.f ? vy : p * vy;
    *(float2*)(out + (size_t)wid * D + 2 * lane) = make_float2(vx, vy);
}

extern "C" void kernel_launch(void* const* d_in, const int* in_sizes, int n_in,
                              void* d_out, int out_size, void* d_ws, size_t ws_size,
                              hipStream_t stream) {
    const float* seq = (const float*)d_in[0];
    const int*   ei  = (const int*)d_in[1];   // [2, E]: row = ei, col = ei + E
    const float* W   = (const float*)d_in[2];
    const float* b   = (const float*)d_in[3];
    const float* pw  = (const float*)d_in[4];
    int n = in_sizes[0] / D;
    int E = in_sizes[1] / 2;

    float* out = (float*)d_out;

    // workspace layout (256B-aligned chunks) — same footprint as R2
    auto align = [](size_t x) { return (x + 255) & ~(size_t)255; };
    char* p = (char*)d_ws;
    float* y    = (float*)p;  p += align((size_t)n * D * sizeof(float));
    int*   deg  = (int*)p;    p += align((size_t)n * sizeof(int));
    float* dinv = (float*)p;  p += align((size_t)n * sizeof(float));
    int*   strt = (int*)p;    p += align((size_t)n * sizeof(int));
    int*   curs = (int*)p;    p += align((size_t)n * sizeof(int));
    int*   bsum = (int*)p;    p += align(64 * sizeof(int));
    int*   srow = (int*)p;    p += align((size_t)E * sizeof(int));

    int nb = (n + 1023) / 1024;   // scan1 blocks (<= 64 for scan2)

    hipMemsetAsync(deg, 0, (size_t)n * sizeof(int), stream);
    k_deg<<<(E + 255) / 256, 256, 0, stream>>>(ei + E, deg, E);
    k_scan1<<<nb, 256, 0, stream>>>(deg, strt, bsum, n);
    k_scan2<<<1, 64, 0, stream>>>(bsum, nb);
    k_scan3<<<(n + 255) / 256, 256, 0, stream>>>(strt, bsum, curs, deg, dinv, n);

    int placeBlocks = 512;
    int gemmBlocks  = (n + 31) / 32;
    k_place_gemm<<<placeBlocks + gemmBlocks, 256, 0, stream>>>(
        ei, ei + E, curs, srow, E, placeBlocks, seq, W, dinv, y, n);

    k_agg<<<(unsigned)(((long long)n * 64 + 255) / 256), 256, 0, stream>>>(
        srow, strt, deg, y, dinv, b, pw, out, n);
}

// Round 4
// 136.095 us; speedup vs baseline: 10.6126x; 1.3091x over previous
//
#include <hip/hip_runtime.h>

constexpr int D = 128;

__device__ __forceinline__ unsigned short f2bf(float f) {   // RNE f32->bf16
    unsigned u = __float_as_uint(f);
    u += 0x7fffu + ((u >> 16) & 1u);
    return (unsigned short)(u >> 16);
}

// ---------------- degree histogram of edge targets ----------------
__global__ __launch_bounds__(256) void k_deg(const int* __restrict__ col,
                                             int* __restrict__ deg, int E) {
    int i = blockIdx.x * 256 + threadIdx.x;
    if (i < E) atomicAdd(&deg[col[i]], 1);
}

// ---------------- scan step 1: per-block (1024 elems) exclusive scan ----------------
__global__ __launch_bounds__(256) void k_scan1(const int* __restrict__ deg,
                                               int* __restrict__ start,
                                               int* __restrict__ bsum, int n) {
    int tid = threadIdx.x;
    int lane = tid & 63, wv = tid >> 6;
    int i0 = (blockIdx.x * 256 + tid) * 4;
    int4 v = {0, 0, 0, 0};
    if (i0 + 3 < n) {
        v = *(const int4*)(deg + i0);
    } else {
        if (i0 < n)     v.x = deg[i0];
        if (i0 + 1 < n) v.y = deg[i0 + 1];
        if (i0 + 2 < n) v.z = deg[i0 + 2];
        if (i0 + 3 < n) v.w = deg[i0 + 3];
    }
    int tsum = v.x + v.y + v.z + v.w;
    int x = tsum;
    #pragma unroll
    for (int off = 1; off < 64; off <<= 1) {
        int t = __shfl_up(x, off);
        if (lane >= off) x += t;
    }
    __shared__ int ws[4];
    if (lane == 63) ws[wv] = x;
    __syncthreads();
    int woff = 0;
    #pragma unroll
    for (int w = 0; w < 3; ++w) if (w < wv) woff += ws[w];
    int ex = woff + x - tsum;
    if (i0 < n)     start[i0]     = ex;
    if (i0 + 1 < n) start[i0 + 1] = ex + v.x;
    if (i0 + 2 < n) start[i0 + 2] = ex + v.x + v.y;
    if (i0 + 3 < n) start[i0 + 3] = ex + v.x + v.y + v.z;
    if (tid == 255) bsum[blockIdx.x] = woff + x;
}

// ---------------- scan step 2: exclusive scan of <=64 block sums ----------------
__global__ __launch_bounds__(64) void k_scan2(int* __restrict__ bsum, int nb) {
    int lane = threadIdx.x;
    int v = (lane < nb) ? bsum[lane] : 0;
    int x = v;
    #pragma unroll
    for (int off = 1; off < 64; off <<= 1) {
        int t = __shfl_up(x, off);
        if (lane >= off) x += t;
    }
    if (lane < nb) bsum[lane] = x - v;
}

// ---------------- scan step 3: add block offsets; init cursor & dinv ----------------
__global__ __launch_bounds__(256) void k_scan3(int* __restrict__ start,
                                               const int* __restrict__ bsum,
                                               int* __restrict__ cursor,
                                               const int* __restrict__ deg,
                                               float* __restrict__ dinv, int n) {
    int i = blockIdx.x * 256 + threadIdx.x;
    if (i >= n) return;
    int s = start[i] + bsum[i >> 10];
    start[i] = s;
    cursor[i] = s;
    dinv[i] = rsqrtf((float)(deg[i] + 1));
}

// ---------------- hybrid: edge placement || GEMM, round-robin interleaved ----------------
// b%3==0 -> GEMM tile block (b/3); else -> placement block (one edge per thread)
__global__ __launch_bounds__(256) void k_place_gemm(
        const int* __restrict__ row, const int* __restrict__ col,
        int* __restrict__ cursor, int* __restrict__ srow, int E,
        int gemmBlocks,
        const float* __restrict__ seq, const float* __restrict__ W,
        const float* __restrict__ dinv, unsigned short* __restrict__ y16, int n) {
    __shared__ float sW[32 * D];   // 16 KB: one 32-k-row chunk of W
    __shared__ float sS[32 * D];   // 16 KB: 32 seq rows

    int bIdx = (int)blockIdx.x;
    int gIdx = bIdx / 3, rem = bIdx % 3;
    bool isGemm = (rem == 0) && (gIdx < gemmBlocks);

    if (!isGemm) {
        int gemmBefore = gIdx + (rem > 0 ? 1 : 0);
        if (gemmBefore > gemmBlocks) gemmBefore = gemmBlocks;
        int placeIdx = bIdx - gemmBefore;
        int e = placeIdx * 256 + threadIdx.x;
        if (e < E) {
            int c = col[e];
            int p = atomicAdd(&cursor[c], 1);
            srow[p] = row[e];
        }
        return;
    }

    // ---- GEMM path: y16[i][:] = bf16( (seq[i] @ W) * dinv[i] ) ----
    int row0 = gIdx * 32;
    int rows = n - row0; if (rows > 32) rows = 32;

    {   // stage seq tile
        const float4* src = (const float4*)(seq + (size_t)row0 * D);
        float4* dst = (float4*)sS;
        int nf4 = rows * (D / 4);
        for (int i = threadIdx.x; i < nf4; i += 256) dst[i] = src[i];
    }

    int cg = threadIdx.x & 31;    // col quad: d = cg*4 .. cg*4+3
    int rg = threadIdx.x >> 5;    // row group: rows rg*4 .. rg*4+3
    float4 acc[4];
    #pragma unroll
    for (int j = 0; j < 4; ++j) acc[j] = make_float4(0.f, 0.f, 0.f, 0.f);

    for (int kc = 0; kc < 4; ++kc) {
        __syncthreads();
        {   // stage 32 k-rows of W
            const float4* src = (const float4*)(W + (size_t)kc * 32 * D);
            float4* dst = (float4*)sW;
            #pragma unroll
            for (int t = 0; t < 4; ++t) dst[threadIdx.x + 256 * t] = src[threadIdx.x + 256 * t];
        }
        __syncthreads();
        int kbase = kc * 32;
        #pragma unroll 4
        for (int k2 = 0; k2 < 32; ++k2) {
            float4 w = *(const float4*)(sW + k2 * D + cg * 4);
            int k = kbase + k2;
            #pragma unroll
            for (int j = 0; j < 4; ++j) {
                float s = sS[(rg * 4 + j) * D + k];   // wave-broadcast read
                acc[j].x += s * w.x;
                acc[j].y += s * w.y;
                acc[j].z += s * w.z;
                acc[j].w += s * w.w;
            }
        }
    }

    #pragma unroll
    for (int j = 0; j < 4; ++j) {
        int g = row0 + rg * 4 + j;
        if (g < n) {
            float di = dinv[g];
            ushort4 o;
            o.x = f2bf(acc[j].x * di);
            o.y = f2bf(acc[j].y * di);
            o.z = f2bf(acc[j].z * di);
            o.w = f2bf(acc[j].w * di);
            *(ushort4*)(y16 + (size_t)g * D + cg * 4) = o;
        }
    }
}

// ---------------- per-node gather-reduce + bias + PReLU ----------------
// out[c] = prelu( dinv[c] * ( y[c] + sum_{e: col=c} y[srow[e]] ) + b )
__global__ __launch_bounds__(256) void k_agg(const int* __restrict__ srow,
                                             const int* __restrict__ start,
                                             const int* __restrict__ deg,
                                             const unsigned short* __restrict__ y16,
                                             const float* __restrict__ dinv,
                                             const float* __restrict__ b,
                                             const float* __restrict__ pw,
                                             float* __restrict__ out, int n) {
    int wid = (blockIdx.x * 256 + threadIdx.x) >> 6;   // one wave per node
    if (wid >= n) return;
    int lane = threadIdx.x & 63;

    int s = start[wid];
    int cnt = deg[wid];

    // self-loop term; lane owns cols 2*lane, 2*lane+1 (one 4B uint = 2 bf16)
    unsigned sv = *(const unsigned*)(y16 + (size_t)wid * D + 2 * lane);
    float ax0 = __uint_as_float(sv << 16), ay0 = __uint_as_float(sv & 0xffff0000u);
    float ax1 = 0.f, ay1 = 0.f, ax2 = 0.f, ay2 = 0.f, ax3 = 0.f, ay3 = 0.f;
    float ax4 = 0.f, ay4 = 0.f, ax5 = 0.f, ay5 = 0.f, ax6 = 0.f, ay6 = 0.f;
    float ax7 = 0.f, ay7 = 0.f;

    for (int base = 0; base < cnt; base += 64) {
        int chunk = cnt - base; if (chunk > 64) chunk = 64;
        int my = (base + lane < cnt) ? srow[s + base + lane] : 0;
        int k = 0;
        for (; k + 7 < chunk; k += 8) {   // 8 independent gathers in flight
            int r0 = __shfl(my, k);
            int r1 = __shfl(my, k + 1);
            int r2 = __shfl(my, k + 2);
            int r3 = __shfl(my, k + 3);
            int r4 = __shfl(my, k + 4);
            int r5 = __shfl(my, k + 5);
            int r6 = __shfl(my, k + 6);
            int r7 = __shfl(my, k + 7);
            unsigned v0 = *(const unsigned*)(y16 + (size_t)r0 * D + 2 * lane);
            unsigned v1 = *(const unsigned*)(y16 + (size_t)r1 * D + 2 * lane);
            unsigned v2 = *(const unsigned*)(y16 + (size_t)r2 * D + 2 * lane);
            unsigned v3 = *(const unsigned*)(y16 + (size_t)r3 * D + 2 * lane);
            unsigned v4 = *(const unsigned*)(y16 + (size_t)r4 * D + 2 * lane);
            unsigned v5 = *(const unsigned*)(y16 + (size_t)r5 * D + 2 * lane);
            unsigned v6 = *(const unsigned*)(y16 + (size_t)r6 * D + 2 * lane);
            unsigned v7 = *(const unsigned*)(y16 + (size_t)r7 * D + 2 * lane);
            ax0 += __uint_as_float(v0 << 16); ay0 += __uint_as_float(v0 & 0xffff0000u);
            ax1 += __uint_as_float(v1 << 16); ay1 += __uint_as_float(v1 & 0xffff0000u);
            ax2 += __uint_as_float(v2 << 16); ay2 += __uint_as_float(v2 & 0xffff0000u);
            ax3 += __uint_as_float(v3 << 16); ay3 += __uint_as_float(v3 & 0xffff0000u);
            ax4 += __uint_as_float(v4 << 16); ay4 += __uint_as_float(v4 & 0xffff0000u);
            ax5 += __uint_as_float(v5 << 16); ay5 += __uint_as_float(v5 & 0xffff0000u);
            ax6 += __uint_as_float(v6 << 16); ay6 += __uint_as_float(v6 & 0xffff0000u);
            ax7 += __uint_as_float(v7 << 16); ay7 += __uint_as_float(v7 & 0xffff0000u);
        }
        for (; k < chunk; ++k) {
            int r = __shfl(my, k);
            unsigned v = *(const unsigned*)(y16 + (size_t)r * D + 2 * lane);
            ax0 += __uint_as_float(v << 16); ay0 += __uint_as_float(v & 0xffff0000u);
        }
    }

    float sx = ((ax0 + ax1) + (ax2 + ax3)) + ((ax4 + ax5) + (ax6 + ax7));
    float sy = ((ay0 + ay1) + (ay2 + ay3)) + ((ay4 + ay5) + (ay6 + ay7));

    float di = dinv[wid];
    float2 bb = *(const float2*)(b + 2 * lane);
    float p = pw[0];
    float vx = sx * di + bb.x;
    float vy = sy * di + bb.y;
    vx = vx > 0.f ? vx : p * vx;
    vy = vy > 0.f ? vy : p * vy;
    *(float2*)(out + (size_t)wid * D + 2 * lane) = make_float2(vx, vy);
}

extern "C" void kernel_launch(void* const* d_in, const int* in_sizes, int n_in,
                              void* d_out, int out_size, void* d_ws, size_t ws_size,
                              hipStream_t stream) {
    const float* seq = (const float*)d_in[0];
    const int*   ei  = (const int*)d_in[1];   // [2, E]: row = ei, col = ei + E
    const float* W   = (const float*)d_in[2];
    const float* b   = (const float*)d_in[3];
    const float* pw  = (const float*)d_in[4];
    int n = in_sizes[0] / D;
    int E = in_sizes[1] / 2;

    float* out = (float*)d_out;

    // workspace layout (256B-aligned chunks)
    auto align = [](size_t x) { return (x + 255) & ~(size_t)255; };
    char* p = (char*)d_ws;
    unsigned short* y16 = (unsigned short*)p; p += align((size_t)n * D * sizeof(unsigned short));
    int*   deg  = (int*)p;    p += align((size_t)n * sizeof(int));
    float* dinv = (float*)p;  p += align((size_t)n * sizeof(float));
    int*   strt = (int*)p;    p += align((size_t)n * sizeof(int));
    int*   curs = (int*)p;    p += align((size_t)n * sizeof(int));
    int*   bsum = (int*)p;    p += align(64 * sizeof(int));
    int*   srow = (int*)p;    p += align((size_t)E * sizeof(int));

    int nb = (n + 1023) / 1024;   // scan1 blocks (<= 64 for scan2)

    hipMemsetAsync(deg, 0, (size_t)n * sizeof(int), stream);
    k_deg<<<(E + 255) / 256, 256, 0, stream>>>(ei + E, deg, E);
    k_scan1<<<nb, 256, 0, stream>>>(deg, strt, bsum, n);
    k_scan2<<<1, 64, 0, stream>>>(bsum, nb);
    k_scan3<<<(n + 255) / 256, 256, 0, stream>>>(strt, bsum, curs, deg, dinv, n);

    int placeBlocks = (E + 255) / 256;        // 3125
    int gemmBlocks  = (n + 31) / 32;          // 1563
    k_place_gemm<<<placeBlocks + gemmBlocks, 256, 0, stream>>>(
        ei, ei + E, curs, srow, E, gemmBlocks, seq, W, dinv, y16, n);

    k_agg<<<(unsigned)(((long long)n * 64 + 255) / 256), 256, 0, stream>>>(
        srow, strt, deg, y16, dinv, b, pw, out, n);
}

// Round 5
// 109.638 us; speedup vs baseline: 13.1736x; 1.2413x over previous
//
#include <hip/hip_runtime.h>

constexpr int D = 128;
constexpr int CAP = 64;         // slots per node; max degree for this input ~40 (Poisson λ=16)
constexpr int OVFCAP = 65536;   // overflow safety list (empty in practice)

__device__ __forceinline__ unsigned short f2bf(float f) {   // RNE f32->bf16
    unsigned u = __float_as_uint(f);
    u += 0x7fffu + ((u >> 16) & 1u);
    return (unsigned short)(u >> 16);
}

// ---------------- hybrid: slot placement (+degree) || GEMM ----------------
// even b < 2*gemmBlocks  -> GEMM tile b/2 : y16[g][:] = bf16(seq[g] @ W)
// otherwise              -> placement: slots[col[e]*CAP + deg[col[e]]++] = row[e]
__global__ __launch_bounds__(256) void k_place_gemm(
        const int* __restrict__ row, const int* __restrict__ col,
        int* __restrict__ deg, int* __restrict__ slots,
        int* __restrict__ ovfCnt, int2* __restrict__ ovf, int E,
        int gemmBlocks,
        const float* __restrict__ seq, const float* __restrict__ W,
        unsigned short* __restrict__ y16, int n) {
    __shared__ float sS[32 * D];   // 16 KB: 32 seq rows (W comes from L2)

    int b = (int)blockIdx.x;
    int half = b >> 1;
    bool isGemm = ((b & 1) == 0) && (half < gemmBlocks);

    if (!isGemm) {
        // placement block index: odd b<2*GB -> b>>1 ; b>=2*GB -> b-GB
        int pIdx = (b < 2 * gemmBlocks) ? half : (b - gemmBlocks);
        int e = pIdx * 256 + threadIdx.x;
        if (e < E) {
            int c = col[e];
            int r = row[e];
            int p = atomicAdd(&deg[c], 1);
            if (p < CAP) {
                slots[(size_t)c * CAP + p] = r;
            } else {
                int o = atomicAdd(ovfCnt, 1);
                if (o < OVFCAP) ovf[o] = make_int2(r, c);
            }
        }
        return;
    }

    // ---- GEMM path ----
    int row0 = half * 32;
    int rows = n - row0; if (rows > 32) rows = 32;

    {   // stage seq tile
        const float4* src = (const float4*)(seq + (size_t)row0 * D);
        float4* dst = (float4*)sS;
        int nf4 = rows * (D / 4);
        for (int i = threadIdx.x; i < nf4; i += 256) dst[i] = src[i];
    }
    __syncthreads();

    int cg = threadIdx.x & 31;    // col quad: d = cg*4 .. cg*4+3
    int rg = threadIdx.x >> 5;    // row group: rows rg*4 .. rg*4+3
    const float4* W4 = (const float4*)W;   // [k][32] float4 rows

    float4 acc[4];
    #pragma unroll
    for (int j = 0; j < 4; ++j) acc[j] = make_float4(0.f, 0.f, 0.f, 0.f);

    #pragma unroll 4
    for (int k = 0; k < D; ++k) {
        float4 w = W4[k * 32 + cg];        // coalesced, L2-hot (W = 64 KB)
        #pragma unroll
        for (int j = 0; j < 4; ++j) {
            float s = sS[(rg * 4 + j) * D + k];   // 2-way wave broadcast
            acc[j].x = fmaf(s, w.x, acc[j].x);
            acc[j].y = fmaf(s, w.y, acc[j].y);
            acc[j].z = fmaf(s, w.z, acc[j].z);
            acc[j].w = fmaf(s, w.w, acc[j].w);
        }
    }

    #pragma unroll
    for (int j = 0; j < 4; ++j) {
        int g = row0 + rg * 4 + j;
        if (g < n) {
            ushort4 o;
            o.x = f2bf(acc[j].x);
            o.y = f2bf(acc[j].y);
            o.z = f2bf(acc[j].z);
            o.w = f2bf(acc[j].w);
            *(ushort4*)(y16 + (size_t)g * D + cg * 4) = o;
        }
    }
}

// ---------------- per-node gather-reduce + norm + bias + PReLU ----------------
// out[c] = prelu( dc * ( sum_e xW[r_e]*dr_e + xW[c]*dc ) + b ),  d* = rsqrt(deg+1)
__global__ __launch_bounds__(256) void k_agg(
        const int* __restrict__ slots, const int* __restrict__ deg,
        const int* __restrict__ ovfCnt, const int2* __restrict__ ovf,
        const unsigned short* __restrict__ y16,
        const float* __restrict__ b, const float* __restrict__ pw,
        float* __restrict__ out, int n) {
    int wid = (blockIdx.x * 256 + threadIdx.x) >> 6;   // one wave per node
    if (wid >= n) return;
    int lane = threadIdx.x & 63;

    int cntf = deg[wid];
    int cnt = cntf < CAP ? cntf : CAP;
    float dc = rsqrtf((float)(cntf + 1));

    // self-loop term; lane owns cols 2*lane, 2*lane+1
    unsigned sv = *(const unsigned*)(y16 + (size_t)wid * D + 2 * lane);
    float ax0 = __uint_as_float(sv << 16) * dc;
    float ay0 = __uint_as_float(sv & 0xffff0000u) * dc;
    float ax1 = 0.f, ay1 = 0.f, ax2 = 0.f, ay2 = 0.f, ax3 = 0.f, ay3 = 0.f;
    float ax4 = 0.f, ay4 = 0.f, ax5 = 0.f, ay5 = 0.f, ax6 = 0.f, ay6 = 0.f;
    float ax7 = 0.f, ay7 = 0.f;

    int my = (lane < cnt) ? slots[(size_t)wid * CAP + lane] : 0;

    int k = 0;
    for (; k + 7 < cnt; k += 8) {   // 8 independent gather chains in flight
        int r0 = __shfl(my, k);
        int r1 = __shfl(my, k + 1);
        int r2 = __shfl(my, k + 2);
        int r3 = __shfl(my, k + 3);
        int r4 = __shfl(my, k + 4);
        int r5 = __shfl(my, k + 5);
        int r6 = __shfl(my, k + 6);
        int r7 = __shfl(my, k + 7);
        int g0 = deg[r0]; int g1 = deg[r1]; int g2 = deg[r2]; int g3 = deg[r3];
        int g4 = deg[r4]; int g5 = deg[r5]; int g6 = deg[r6]; int g7 = deg[r7];
        unsigned v0 = *(const unsigned*)(y16 + (size_t)r0 * D + 2 * lane);
        unsigned v1 = *(const unsigned*)(y16 + (size_t)r1 * D + 2 * lane);
        unsigned v2 = *(const unsigned*)(y16 + (size_t)r2 * D + 2 * lane);
        unsigned v3 = *(const unsigned*)(y16 + (size_t)r3 * D + 2 * lane);
        unsigned v4 = *(const unsigned*)(y16 + (size_t)r4 * D + 2 * lane);
        unsigned v5 = *(const unsigned*)(y16 + (size_t)r5 * D + 2 * lane);
        unsigned v6 = *(const unsigned*)(y16 + (size_t)r6 * D + 2 * lane);
        unsigned v7 = *(const unsigned*)(y16 + (size_t)r7 * D + 2 * lane);
        float dr0 = rsqrtf((float)(g0 + 1));
        float dr1 = rsqrtf((float)(g1 + 1));
        float dr2 = rsqrtf((float)(g2 + 1));
        float dr3 = rsqrtf((float)(g3 + 1));
        float dr4 = rsqrtf((float)(g4 + 1));
        float dr5 = rsqrtf((float)(g5 + 1));
        float dr6 = rsqrtf((float)(g6 + 1));
        float dr7 = rsqrtf((float)(g7 + 1));
        ax0 = fmaf(__uint_as_float(v0 << 16), dr0, ax0); ay0 = fmaf(__uint_as_float(v0 & 0xffff0000u), dr0, ay0);
        ax1 = fmaf(__uint_as_float(v1 << 16), dr1, ax1); ay1 = fmaf(__uint_as_float(v1 & 0xffff0000u), dr1, ay1);
        ax2 = fmaf(__uint_as_float(v2 << 16), dr2, ax2); ay2 = fmaf(__uint_as_float(v2 & 0xffff0000u), dr2, ay2);
        ax3 = fmaf(__uint_as_float(v3 << 16), dr3, ax3); ay3 = fmaf(__uint_as_float(v3 & 0xffff0000u), dr3, ay3);
        ax4 = fmaf(__uint_as_float(v4 << 16), dr4, ax4); ay4 = fmaf(__uint_as_float(v4 & 0xffff0000u), dr4, ay4);
        ax5 = fmaf(__uint_as_float(v5 << 16), dr5, ax5); ay5 = fmaf(__uint_as_float(v5 & 0xffff0000u), dr5, ay5);
        ax6 = fmaf(__uint_as_float(v6 << 16), dr6, ax6); ay6 = fmaf(__uint_as_float(v6 & 0xffff0000u), dr6, ay6);
        ax7 = fmaf(__uint_as_float(v7 << 16), dr7, ax7); ay7 = fmaf(__uint_as_float(v7 & 0xffff0000u), dr7, ay7);
    }
    for (; k < cnt; ++k) {
        int r = __shfl(my, k);
        float dr = rsqrtf((float)(deg[r] + 1));
        unsigned v = *(const unsigned*)(y16 + (size_t)r * D + 2 * lane);
        ax0 = fmaf(__uint_as_float(v << 16), dr, ax0);
        ay0 = fmaf(__uint_as_float(v & 0xffff0000u), dr, ay0);
    }

    if (cntf > CAP) {   // overflow drain (never taken for this input; correctness net)
        int m = *ovfCnt; if (m > OVFCAP) m = OVFCAP;
        for (int j = 0; j < m; ++j) {
            int2 pr = ovf[j];
            if (pr.y == wid) {
                float dr = rsqrtf((float)(deg[pr.x] + 1));
                unsigned v = *(const unsigned*)(y16 + (size_t)pr.x * D + 2 * lane);
                ax0 = fmaf(__uint_as_float(v << 16), dr, ax0);
                ay0 = fmaf(__uint_as_float(v & 0xffff0000u), dr, ay0);
            }
        }
    }

    float sx = ((ax0 + ax1) + (ax2 + ax3)) + ((ax4 + ax5) + (ax6 + ax7));
    float sy = ((ay0 + ay1) + (ay2 + ay3)) + ((ay4 + ay5) + (ay6 + ay7));

    float2 bb = *(const float2*)(b + 2 * lane);
    float p = pw[0];
    float vx = sx * dc + bb.x;
    float vy = sy * dc + bb.y;
    vx = vx > 0.f ? vx : p * vx;
    vy = vy > 0.f ? vy : p * vy;
    *(float2*)(out + (size_t)wid * D + 2 * lane) = make_float2(vx, vy);
}

extern "C" void kernel_launch(void* const* d_in, const int* in_sizes, int n_in,
                              void* d_out, int out_size, void* d_ws, size_t ws_size,
                              hipStream_t stream) {
    const float* seq = (const float*)d_in[0];
    const int*   ei  = (const int*)d_in[1];   // [2, E]: row = ei, col = ei + E
    const float* W   = (const float*)d_in[2];
    const float* b   = (const float*)d_in[3];
    const float* pw  = (const float*)d_in[4];
    int n = in_sizes[0] / D;
    int E = in_sizes[1] / 2;

    float* out = (float*)d_out;

    // workspace layout (256B-aligned chunks): ~26.5 MB
    auto align = [](size_t x) { return (x + 255) & ~(size_t)255; };
    char* p = (char*)d_ws;
    unsigned short* y16 = (unsigned short*)p; p += align((size_t)n * D * sizeof(unsigned short));
    int*  deg    = (int*)p;   size_t degBytes = align((size_t)n * sizeof(int)); p += degBytes;
    int*  ovfCnt = (int*)p;   p += 256;
    int2* ovf    = (int2*)p;  p += align((size_t)OVFCAP * sizeof(int2));
    int*  slots  = (int*)p;   p += align((size_t)n * CAP * sizeof(int));

    // zero deg + ovfCnt in one memset (contiguous)
    hipMemsetAsync(deg, 0, degBytes + 256, stream);

    int GB = (n + 31) / 32;        // 1563 GEMM tiles
    int PB = (E + 255) / 256;      // 3125 placement blocks
    k_place_gemm<<<GB + PB, 256, 0, stream>>>(
        ei, ei + E, deg, slots, ovfCnt, ovf, E, GB, seq, W, y16, n);

    k_agg<<<(unsigned)(((long long)n * 64 + 255) / 256), 256, 0, stream>>>(
        slots, deg, ovfCnt, ovf, y16, b, pw, out, n);
}

// Round 6
// 100.336 us; speedup vs baseline: 14.3948x; 1.0927x over previous
//
#include <hip/hip_runtime.h>

constexpr int D = 128;
constexpr int CAP = 64;         // slots per node; max degree for this input ~40 (Poisson λ=16)
constexpr int OVFCAP = 65536;   // overflow safety list (empty in practice)

__device__ __forceinline__ unsigned short f2bf(float f) {   // RNE f32->bf16
    unsigned u = __float_as_uint(f);
    u += 0x7fffu + ((u >> 16) & 1u);
    return (unsigned short)(u >> 16);
}

// ---------------- hybrid: slot placement (+degree) || GEMM ----------------
// even b, b/2 < gemmBlocks -> GEMM 64-row tile b/2 : y16[g][:] = bf16(seq[g] @ W)
// otherwise                -> placement: 2 edges/thread, slots[c*CAP + deg[c]++] = r
__global__ __launch_bounds__(256) void k_place_gemm(
        const int* __restrict__ row, const int* __restrict__ col,
        int* __restrict__ deg, int* __restrict__ slots,
        int* __restrict__ ovfCnt, int2* __restrict__ ovf, int E,
        int gemmBlocks,
        const float* __restrict__ seq, const float* __restrict__ W,
        unsigned short* __restrict__ y16, int n) {
    __shared__ float sS[64 * D];   // 32 KB: 64 seq rows
    __shared__ float sW[16 * D];   // 8 KB: one 16-k-row chunk of W

    int b = (int)blockIdx.x;
    int half = b >> 1;
    bool isGemm = ((b & 1) == 0) && (half < gemmBlocks);

    if (!isGemm) {
        // placement block index: odd b<2*GB -> b>>1 ; b>=2*GB -> b-GB
        int pIdx = (b < 2 * gemmBlocks) ? half : (b - gemmBlocks);
        int t = pIdx * 256 + threadIdx.x;
        int e = 2 * t;
        if (e + 1 < E) {
            int2 c2 = *(const int2*)(col + e);
            int2 r2 = *(const int2*)(row + e);
            int p0 = atomicAdd(&deg[c2.x], 1);   // two independent chains
            int p1 = atomicAdd(&deg[c2.y], 1);
            if (p0 < CAP) slots[(size_t)c2.x * CAP + p0] = r2.x;
            else { int o = atomicAdd(ovfCnt, 1); if (o < OVFCAP) ovf[o] = make_int2(r2.x, c2.x); }
            if (p1 < CAP) slots[(size_t)c2.y * CAP + p1] = r2.y;
            else { int o = atomicAdd(ovfCnt, 1); if (o < OVFCAP) ovf[o] = make_int2(r2.y, c2.y); }
        } else if (e < E) {
            int c = col[e];
            int r = row[e];
            int p = atomicAdd(&deg[c], 1);
            if (p < CAP) slots[(size_t)c * CAP + p] = r;
            else { int o = atomicAdd(ovfCnt, 1); if (o < OVFCAP) ovf[o] = make_int2(r, c); }
        }
        return;
    }

    // ---- GEMM path: 64-row tile ----
    int row0 = half * 64;
    int rows = n - row0; if (rows > 64) rows = 64;

    {   // stage seq tile (uninit LDS beyond 'rows' never stored: stores are guarded)
        const float4* src = (const float4*)(seq + (size_t)row0 * D);
        float4* dst = (float4*)sS;
        int nf4 = rows * (D / 4);
        for (int i = threadIdx.x; i < nf4; i += 256) dst[i] = src[i];
    }

    int cg = threadIdx.x & 31;    // col quad: d = cg*4 .. cg*4+3
    int rg = threadIdx.x >> 5;    // row group: rows rg*8 .. rg*8+7
    float4 acc[8];
    #pragma unroll
    for (int j = 0; j < 8; ++j) acc[j] = make_float4(0.f, 0.f, 0.f, 0.f);

    for (int kc = 0; kc < 8; ++kc) {
        __syncthreads();          // also covers sS staging on kc==0
        {   // stage 16 k-rows of W (512 float4)
            const float4* wsrc = (const float4*)(W + (size_t)kc * 16 * D);
            float4* wdst = (float4*)sW;
            wdst[threadIdx.x]       = wsrc[threadIdx.x];
            wdst[threadIdx.x + 256] = wsrc[threadIdx.x + 256];
        }
        __syncthreads();
        int kbase = kc * 16;
        #pragma unroll
        for (int k2 = 0; k2 < 16; ++k2) {
            float4 w = ((const float4*)sW)[k2 * 32 + cg];
            int k = kbase + k2;
            #pragma unroll
            for (int j = 0; j < 8; ++j) {
                float s = sS[(rg * 8 + j) * D + k];   // 2 addrs/wave: broadcast
                acc[j].x = fmaf(s, w.x, acc[j].x);
                acc[j].y = fmaf(s, w.y, acc[j].y);
                acc[j].z = fmaf(s, w.z, acc[j].z);
                acc[j].w = fmaf(s, w.w, acc[j].w);
            }
        }
    }

    #pragma unroll
    for (int j = 0; j < 8; ++j) {
        int g = row0 + rg * 8 + j;
        if (g < n) {
            ushort4 o;
            o.x = f2bf(acc[j].x);
            o.y = f2bf(acc[j].y);
            o.z = f2bf(acc[j].z);
            o.w = f2bf(acc[j].w);
            *(ushort4*)(y16 + (size_t)g * D + cg * 4) = o;
        }
    }
}

// ---------------- per-node gather-reduce + norm + bias + PReLU ----------------
// out[c] = prelu( dc * ( sum_e xW[r_e]*dr_e + xW[c]*dc ) + b ),  d* = rsqrt(deg+1)
__global__ __launch_bounds__(256) void k_agg(
        const int* __restrict__ slots, const int* __restrict__ deg,
        const int* __restrict__ ovfCnt, const int2* __restrict__ ovf,
        const unsigned short* __restrict__ y16,
        const float* __restrict__ b, const float* __restrict__ pw,
        float* __restrict__ out, int n) {
    int wid = (blockIdx.x * 256 + threadIdx.x) >> 6;   // one wave per node
    if (wid >= n) return;
    int lane = threadIdx.x & 63;

    int cntf = deg[wid];
    int cnt = cntf < CAP ? cntf : CAP;
    float dc = rsqrtf((float)(cntf + 1));

    // self-loop term; lane owns cols 2*lane, 2*lane+1
    unsigned sv = *(const unsigned*)(y16 + (size_t)wid * D + 2 * lane);
    float ax0 = __uint_as_float(sv << 16) * dc;
    float ay0 = __uint_as_float(sv & 0xffff0000u) * dc;
    float ax1 = 0.f, ay1 = 0.f, ax2 = 0.f, ay2 = 0.f, ax3 = 0.f, ay3 = 0.f;
    float ax4 = 0.f, ay4 = 0.f, ax5 = 0.f, ay5 = 0.f, ax6 = 0.f, ay6 = 0.f;
    float ax7 = 0.f, ay7 = 0.f;

    int my = (lane < cnt) ? slots[(size_t)wid * CAP + lane] : 0;

    int k = 0;
    for (; k + 7 < cnt; k += 8) {   // 8 independent gather chains in flight
        int r0 = __shfl(my, k);
        int r1 = __shfl(my, k + 1);
        int r2 = __shfl(my, k + 2);
        int r3 = __shfl(my, k + 3);
        int r4 = __shfl(my, k + 4);
        int r5 = __shfl(my, k + 5);
        int r6 = __shfl(my, k + 6);
        int r7 = __shfl(my, k + 7);
        int g0 = deg[r0]; int g1 = deg[r1]; int g2 = deg[r2]; int g3 = deg[r3];
        int g4 = deg[r4]; int g5 = deg[r5]; int g6 = deg[r6]; int g7 = deg[r7];
        unsigned v0 = *(const unsigned*)(y16 + (size_t)r0 * D + 2 * lane);
        unsigned v1 = *(const unsigned*)(y16 + (size_t)r1 * D + 2 * lane);
        unsigned v2 = *(const unsigned*)(y16 + (size_t)r2 * D + 2 * lane);
        unsigned v3 = *(const unsigned*)(y16 + (size_t)r3 * D + 2 * lane);
        unsigned v4 = *(const unsigned*)(y16 + (size_t)r4 * D + 2 * lane);
        unsigned v5 = *(const unsigned*)(y16 + (size_t)r5 * D + 2 * lane);
        unsigned v6 = *(const unsigned*)(y16 + (size_t)r6 * D + 2 * lane);
        unsigned v7 = *(const unsigned*)(y16 + (size_t)r7 * D + 2 * lane);
        float dr0 = rsqrtf((float)(g0 + 1));
        float dr1 = rsqrtf((float)(g1 + 1));
        float dr2 = rsqrtf((float)(g2 + 1));
        float dr3 = rsqrtf((float)(g3 + 1));
        float dr4 = rsqrtf((float)(g4 + 1));
        float dr5 = rsqrtf((float)(g5 + 1));
        float dr6 = rsqrtf((float)(g6 + 1));
        float dr7 = rsqrtf((float)(g7 + 1));
        ax0 = fmaf(__uint_as_float(v0 << 16), dr0, ax0); ay0 = fmaf(__uint_as_float(v0 & 0xffff0000u), dr0, ay0);
        ax1 = fmaf(__uint_as_float(v1 << 16), dr1, ax1); ay1 = fmaf(__uint_as_float(v1 & 0xffff0000u), dr1, ay1);
        ax2 = fmaf(__uint_as_float(v2 << 16), dr2, ax2); ay2 = fmaf(__uint_as_float(v2 & 0xffff0000u), dr2, ay2);
        ax3 = fmaf(__uint_as_float(v3 << 16), dr3, ax3); ay3 = fmaf(__uint_as_float(v3 & 0xffff0000u), dr3, ay3);
        ax4 = fmaf(__uint_as_float(v4 << 16), dr4, ax4); ay4 = fmaf(__uint_as_float(v4 & 0xffff0000u), dr4, ay4);
        ax5 = fmaf(__uint_as_float(v5 << 16), dr5, ax5); ay5 = fmaf(__uint_as_float(v5 & 0xffff0000u), dr5, ay5);
        ax6 = fmaf(__uint_as_float(v6 << 16), dr6, ax6); ay6 = fmaf(__uint_as_float(v6 & 0xffff0000u), dr6, ay6);
        ax7 = fmaf(__uint_as_float(v7 << 16), dr7, ax7); ay7 = fmaf(__uint_as_float(v7 & 0xffff0000u), dr7, ay7);
    }
    for (; k < cnt; ++k) {
        int r = __shfl(my, k);
        float dr = rsqrtf((float)(deg[r] + 1));
        unsigned v = *(const unsigned*)(y16 + (size_t)r * D + 2 * lane);
        ax0 = fmaf(__uint_as_float(v << 16), dr, ax0);
        ay0 = fmaf(__uint_as_float(v & 0xffff0000u), dr, ay0);
    }

    if (cntf > CAP) {   // overflow drain (never taken for this input; correctness net)
        int m = *ovfCnt; if (m > OVFCAP) m = OVFCAP;
        for (int j = 0; j < m; ++j) {
            int2 pr = ovf[j];
            if (pr.y == wid) {
                float dr = rsqrtf((float)(deg[pr.x] + 1));
                unsigned v = *(const unsigned*)(y16 + (size_t)pr.x * D + 2 * lane);
                ax0 = fmaf(__uint_as_float(v << 16), dr, ax0);
                ay0 = fmaf(__uint_as_float(v & 0xffff0000u), dr, ay0);
            }
        }
    }

    float sx = ((ax0 + ax1) + (ax2 + ax3)) + ((ax4 + ax5) + (ax6 + ax7));
    float sy = ((ay0 + ay1) + (ay2 + ay3)) + ((ay4 + ay5) + (ay6 + ay7));

    float2 bb = *(const float2*)(b + 2 * lane);
    float p = pw[0];
    float vx = sx * dc + bb.x;
    float vy = sy * dc + bb.y;
    vx = vx > 0.f ? vx : p * vx;
    vy = vy > 0.f ? vy : p * vy;
    *(float2*)(out + (size_t)wid * D + 2 * lane) = make_float2(vx, vy);
}

extern "C" void kernel_launch(void* const* d_in, const int* in_sizes, int n_in,
                              void* d_out, int out_size, void* d_ws, size_t ws_size,
                              hipStream_t stream) {
    const float* seq = (const float*)d_in[0];
    const int*   ei  = (const int*)d_in[1];   // [2, E]: row = ei, col = ei + E
    const float* W   = (const float*)d_in[2];
    const float* b   = (const float*)d_in[3];
    const float* pw  = (const float*)d_in[4];
    int n = in_sizes[0] / D;
    int E = in_sizes[1] / 2;

    float* out = (float*)d_out;

    // workspace layout (256B-aligned chunks): ~26.5 MB
    auto align = [](size_t x) { return (x + 255) & ~(size_t)255; };
    char* p = (char*)d_ws;
    unsigned short* y16 = (unsigned short*)p; p += align((size_t)n * D * sizeof(unsigned short));
    int*  deg    = (int*)p;   size_t degBytes = align((size_t)n * sizeof(int)); p += degBytes;
    int*  ovfCnt = (int*)p;   p += 256;
    int2* ovf    = (int2*)p;  p += align((size_t)OVFCAP * sizeof(int2));
    int*  slots  = (int*)p;   p += align((size_t)n * CAP * sizeof(int));

    // zero deg + ovfCnt in one memset (contiguous)
    hipMemsetAsync(deg, 0, degBytes + 256, stream);

    int GB = (n + 63) / 64;        // 782 GEMM tiles (64 rows)
    int PB = (E + 511) / 512;      // 1563 placement blocks (2 edges/thread)
    k_place_gemm<<<GB + PB, 256, 0, stream>>>(
        ei, ei + E, deg, slots, ovfCnt, ovf, E, GB, seq, W, y16, n);

    k_agg<<<(unsigned)(((long long)n * 64 + 255) / 256), 256, 0, stream>>>(
        slots, deg, ovfCnt, ovf, y16, b, pw, out, n);
}

// Round 7
// 99.369 us; speedup vs baseline: 14.5350x; 1.0097x over previous
//
#include <hip/hip_runtime.h>

constexpr int D = 128;
constexpr int CAP = 64;         // slots per node; max degree for this input ~40 (Poisson λ=16)
constexpr int OVFCAP = 65536;   // overflow safety list (empty in practice)

typedef __attribute__((ext_vector_type(8))) short short8;   // 8 bf16 (4 VGPR)
typedef __attribute__((ext_vector_type(4))) float f32x4;    // MFMA accumulator

__device__ __forceinline__ unsigned short f2bf(float f) {   // RNE f32->bf16
    unsigned u = __float_as_uint(f);
    u += 0x7fffu + ((u >> 16) & 1u);
    return (unsigned short)(u >> 16);
}

// ---------------- prep: W [128x128 f32, k-major] -> Wf fragment-ordered bf16 ----------------
// Wf[((kc*8 + t)*64 + l)*8 + j] = bf16( W[ kc*32 + (l>>4)*4 + (j&3) + (j>>2)*16 ][ t*16 + (l&15) ] )
// so the GEMM's B-fragment for (kc, n-tile t, lane l) is one contiguous 16B load.
__global__ __launch_bounds__(256) void k_prep(const float* __restrict__ W,
                                              unsigned short* __restrict__ Wf) {
    int tid = blockIdx.x * 256 + threadIdx.x;   // 64 blocks x 256 = 16384
    int j  = tid & 7;
    int l  = (tid >> 3) & 63;
    int g  = tid >> 9;          // 0..31 = kc*8 + t
    int kc = g >> 3, t = g & 7;
    int k  = kc * 32 + ((l >> 4) * 4) + (j & 3) + ((j >> 2) * 16);
    int c  = t * 16 + (l & 15);
    Wf[tid] = f2bf(W[k * D + c]);
}

// ---------------- hybrid: slot placement (+degree) || MFMA GEMM (no LDS!) ----------------
// even b, b/2 < gemmBlocks -> GEMM 64-row tile b/2 : y16[g][:] = bf16(seq[g] @ W)
// otherwise                -> placement: 2 edges/thread, slots[c*CAP + deg[c]++] = r
__global__ __launch_bounds__(256) void k_place_gemm(
        const int* __restrict__ row, const int* __restrict__ col,
        int* __restrict__ deg, int* __restrict__ slots,
        int* __restrict__ ovfCnt, int2* __restrict__ ovf, int E,
        int gemmBlocks,
        const float* __restrict__ seq, const unsigned short* __restrict__ Wf,
        unsigned short* __restrict__ y16, int n) {
    int b = (int)blockIdx.x;
    int half = b >> 1;
    bool isGemm = ((b & 1) == 0) && (half < gemmBlocks);

    if (!isGemm) {
        // placement block index: odd b<2*GB -> b>>1 ; b>=2*GB -> b-GB
        int pIdx = (b < 2 * gemmBlocks) ? half : (b - gemmBlocks);
        int t = pIdx * 256 + threadIdx.x;
        int e = 2 * t;
        if (e + 1 < E) {
            int2 c2 = *(const int2*)(col + e);
            int2 r2 = *(const int2*)(row + e);
            int p0 = atomicAdd(&deg[c2.x], 1);   // two independent chains
            int p1 = atomicAdd(&deg[c2.y], 1);
            if (p0 < CAP) slots[(size_t)c2.x * CAP + p0] = r2.x;
            else { int o = atomicAdd(ovfCnt, 1); if (o < OVFCAP) ovf[o] = make_int2(r2.x, c2.x); }
            if (p1 < CAP) slots[(size_t)c2.y * CAP + p1] = r2.y;
            else { int o = atomicAdd(ovfCnt, 1); if (o < OVFCAP) ovf[o] = make_int2(r2.y, c2.y); }
        } else if (e < E) {
            int c = col[e];
            int r = row[e];
            int p = atomicAdd(&deg[c], 1);
            if (p < CAP) slots[(size_t)c * CAP + p] = r;
            else { int o = atomicAdd(ovfCnt, 1); if (o < OVFCAP) ovf[o] = make_int2(r, c); }
        }
        return;
    }

    // ---- GEMM path: 64-row tile, 4 waves x 16 rows, N=128 (8 n-tiles), K=128 (4 chunks) ----
    int w  = threadIdx.x >> 6;    // wave 0..3
    int l  = threadIdx.x & 63;
    int lr = l & 15;              // A-row / C-col within tile
    int lg = l >> 4;              // 0..3

    int row0 = half * 64;
    int m = row0 + w * 16 + lr;
    if (m >= n) m = n - 1;        // clamp (partial last tile; stores guarded below)
    const float* sp = seq + (size_t)m * D;

    f32x4 acc[8];
    #pragma unroll
    for (int t = 0; t < 8; ++t) acc[t] = (f32x4){0.f, 0.f, 0.f, 0.f};

    const short8* WfB = (const short8*)Wf;

    #pragma unroll
    for (int kc = 0; kc < 4; ++kc) {
        int kb = kc * 32 + lg * 4;
        float4 lo = *(const float4*)(sp + kb);        // k = kb..kb+3
        float4 hi = *(const float4*)(sp + kb + 16);   // k = kb+16..kb+19
        short8 a;
        a[0] = (short)f2bf(lo.x); a[1] = (short)f2bf(lo.y);
        a[2] = (short)f2bf(lo.z); a[3] = (short)f2bf(lo.w);
        a[4] = (short)f2bf(hi.x); a[5] = (short)f2bf(hi.y);
        a[6] = (short)f2bf(hi.z); a[7] = (short)f2bf(hi.w);
        #pragma unroll
        for (int t = 0; t < 8; ++t) {
            short8 bf = WfB[(kc * 8 + t) * 64 + l];   // coalesced 16B, L1/L2-hot
            acc[t] = __builtin_amdgcn_mfma_f32_16x16x32_bf16(a, bf, acc[t], 0, 0, 0);
        }
    }

    // C/D: col = lane&15 (= lr), row = (lane>>4)*4 + reg (= lg*4 + i)
    #pragma unroll
    for (int i = 0; i < 4; ++i) {
        int g = row0 + w * 16 + lg * 4 + i;
        if (g < n) {
            unsigned short* yp = y16 + (size_t)g * D + lr;
            #pragma unroll
            for (int t = 0; t < 8; ++t) yp[t * 16] = f2bf(acc[t][i]);
        }
    }
}

// ---------------- per-node gather-reduce + norm + bias + PReLU ----------------
// out[c] = prelu( dc * ( sum_e xW[r_e]*dr_e + xW[c]*dc ) + b ),  d* = rsqrt(deg+1)
__global__ __launch_bounds__(256) void k_agg(
        const int* __restrict__ slots, const int* __restrict__ deg,
        const int* __restrict__ ovfCnt, const int2* __restrict__ ovf,
        const unsigned short* __restrict__ y16,
        const float* __restrict__ b, const float* __restrict__ pw,
        float* __restrict__ out, int n) {
    int wid = (blockIdx.x * 256 + threadIdx.x) >> 6;   // one wave per node
    if (wid >= n) return;
    int lane = threadIdx.x & 63;

    int cntf = deg[wid];
    int cnt = cntf < CAP ? cntf : CAP;
    float dc = rsqrtf((float)(cntf + 1));

    // self-loop term; lane owns cols 2*lane, 2*lane+1
    unsigned sv = *(const unsigned*)(y16 + (size_t)wid * D + 2 * lane);
    float ax0 = __uint_as_float(sv << 16) * dc;
    float ay0 = __uint_as_float(sv & 0xffff0000u) * dc;
    float ax1 = 0.f, ay1 = 0.f, ax2 = 0.f, ay2 = 0.f, ax3 = 0.f, ay3 = 0.f;
    float ax4 = 0.f, ay4 = 0.f, ax5 = 0.f, ay5 = 0.f, ax6 = 0.f, ay6 = 0.f;
    float ax7 = 0.f, ay7 = 0.f;

    int my = (lane < cnt) ? slots[(size_t)wid * CAP + lane] : 0;

    int k = 0;
    for (; k + 7 < cnt; k += 8) {   // 8 independent gather chains in flight
        int r0 = __shfl(my, k);
        int r1 = __shfl(my, k + 1);
        int r2 = __shfl(my, k + 2);
        int r3 = __shfl(my, k + 3);
        int r4 = __shfl(my, k + 4);
        int r5 = __shfl(my, k + 5);
        int r6 = __shfl(my, k + 6);
        int r7 = __shfl(my, k + 7);
        int g0 = deg[r0]; int g1 = deg[r1]; int g2 = deg[r2]; int g3 = deg[r3];
        int g4 = deg[r4]; int g5 = deg[r5]; int g6 = deg[r6]; int g7 = deg[r7];
        unsigned v0 = *(const unsigned*)(y16 + (size_t)r0 * D + 2 * lane);
        unsigned v1 = *(const unsigned*)(y16 + (size_t)r1 * D + 2 * lane);
        unsigned v2 = *(const unsigned*)(y16 + (size_t)r2 * D + 2 * lane);
        unsigned v3 = *(const unsigned*)(y16 + (size_t)r3 * D + 2 * lane);
        unsigned v4 = *(const unsigned*)(y16 + (size_t)r4 * D + 2 * lane);
        unsigned v5 = *(const unsigned*)(y16 + (size_t)r5 * D + 2 * lane);
        unsigned v6 = *(const unsigned*)(y16 + (size_t)r6 * D + 2 * lane);
        unsigned v7 = *(const unsigned*)(y16 + (size_t)r7 * D + 2 * lane);
        float dr0 = rsqrtf((float)(g0 + 1));
        float dr1 = rsqrtf((float)(g1 + 1));
        float dr2 = rsqrtf((float)(g2 + 1));
        float dr3 = rsqrtf((float)(g3 + 1));
        float dr4 = rsqrtf((float)(g4 + 1));
        float dr5 = rsqrtf((float)(g5 + 1));
        float dr6 = rsqrtf((float)(g6 + 1));
        float dr7 = rsqrtf((float)(g7 + 1));
        ax0 = fmaf(__uint_as_float(v0 << 16), dr0, ax0); ay0 = fmaf(__uint_as_float(v0 & 0xffff0000u), dr0, ay0);
        ax1 = fmaf(__uint_as_float(v1 << 16), dr1, ax1); ay1 = fmaf(__uint_as_float(v1 & 0xffff0000u), dr1, ay1);
        ax2 = fmaf(__uint_as_float(v2 << 16), dr2, ax2); ay2 = fmaf(__uint_as_float(v2 & 0xffff0000u), dr2, ay2);
        ax3 = fmaf(__uint_as_float(v3 << 16), dr3, ax3); ay3 = fmaf(__uint_as_float(v3 & 0xffff0000u), dr3, ay3);
        ax4 = fmaf(__uint_as_float(v4 << 16), dr4, ax4); ay4 = fmaf(__uint_as_float(v4 & 0xffff0000u), dr4, ay4);
        ax5 = fmaf(__uint_as_float(v5 << 16), dr5, ax5); ay5 = fmaf(__uint_as_float(v5 & 0xffff0000u), dr5, ay5);
        ax6 = fmaf(__uint_as_float(v6 << 16), dr6, ax6); ay6 = fmaf(__uint_as_float(v6 & 0xffff0000u), dr6, ay6);
        ax7 = fmaf(__uint_as_float(v7 << 16), dr7, ax7); ay7 = fmaf(__uint_as_float(v7 & 0xffff0000u), dr7, ay7);
    }
    for (; k < cnt; ++k) {
        int r = __shfl(my, k);
        float dr = rsqrtf((float)(deg[r] + 1));
        unsigned v = *(const unsigned*)(y16 + (size_t)r * D + 2 * lane);
        ax0 = fmaf(__uint_as_float(v << 16), dr, ax0);
        ay0 = fmaf(__uint_as_float(v & 0xffff0000u), dr, ay0);
    }

    if (cntf > CAP) {   // overflow drain (never taken for this input; correctness net)
        int m = *ovfCnt; if (m > OVFCAP) m = OVFCAP;
        for (int j = 0; j < m; ++j) {
            int2 pr = ovf[j];
            if (pr.y == wid) {
                float dr = rsqrtf((float)(deg[pr.x] + 1));
                unsigned v = *(const unsigned*)(y16 + (size_t)pr.x * D + 2 * lane);
                ax0 = fmaf(__uint_as_float(v << 16), dr, ax0);
                ay0 = fmaf(__uint_as_float(v & 0xffff0000u), dr, ay0);
            }
        }
    }

    float sx = ((ax0 + ax1) + (ax2 + ax3)) + ((ax4 + ax5) + (ax6 + ax7));
    float sy = ((ay0 + ay1) + (ay2 + ay3)) + ((ay4 + ay5) + (ay6 + ay7));

    float2 bb = *(const float2*)(b + 2 * lane);
    float p = pw[0];
    float vx = sx * dc + bb.x;
    float vy = sy * dc + bb.y;
    vx = vx > 0.f ? vx : p * vx;
    vy = vy > 0.f ? vy : p * vy;
    *(float2*)(out + (size_t)wid * D + 2 * lane) = make_float2(vx, vy);
}

extern "C" void kernel_launch(void* const* d_in, const int* in_sizes, int n_in,
                              void* d_out, int out_size, void* d_ws, size_t ws_size,
                              hipStream_t stream) {
    const float* seq = (const float*)d_in[0];
    const int*   ei  = (const int*)d_in[1];   // [2, E]: row = ei, col = ei + E
    const float* W   = (const float*)d_in[2];
    const float* b   = (const float*)d_in[3];
    const float* pw  = (const float*)d_in[4];
    int n = in_sizes[0] / D;
    int E = in_sizes[1] / 2;

    float* out = (float*)d_out;

    // workspace layout (256B-aligned chunks): ~27 MB
    auto align = [](size_t x) { return (x + 255) & ~(size_t)255; };
    char* p = (char*)d_ws;
    unsigned short* y16 = (unsigned short*)p; p += align((size_t)n * D * sizeof(unsigned short));
    int*  deg    = (int*)p;   size_t degBytes = align((size_t)n * sizeof(int)); p += degBytes;
    int*  ovfCnt = (int*)p;   p += 256;
    int2* ovf    = (int2*)p;  p += align((size_t)OVFCAP * sizeof(int2));
    int*  slots  = (int*)p;   p += align((size_t)n * CAP * sizeof(int));
    unsigned short* Wf = (unsigned short*)p; p += align((size_t)D * D * sizeof(unsigned short));

    // zero deg + ovfCnt in one memset (contiguous)
    hipMemsetAsync(deg, 0, degBytes + 256, stream);
    k_prep<<<64, 256, 0, stream>>>(W, Wf);

    int GB = (n + 63) / 64;        // 782 GEMM tiles (64 rows)
    int PB = (E + 511) / 512;      // 1563 placement blocks (2 edges/thread)
    k_place_gemm<<<GB + PB, 256, 0, stream>>>(
        ei, ei + E, deg, slots, ovfCnt, ovf, E, GB, seq, Wf, y16, n);

    k_agg<<<(unsigned)(((long long)n * 64 + 255) / 256), 256, 0, stream>>>(
        slots, deg, ovfCnt, ovf, y16, b, pw, out, n);
}

// Round 8
// 89.405 us; speedup vs baseline: 16.1548x; 1.1114x over previous
//
#include <hip/hip_runtime.h>

constexpr int D = 128;
constexpr int CAP = 48;         // slots per node; max degree for this input ~40 (Poisson λ=16)
constexpr int DPAD = 16;        // deg counter stride (ints): one counter per 64B line
constexpr int OVFCAP = 65536;   // overflow safety list (empty in practice)

typedef __attribute__((ext_vector_type(8))) short short8;   // 8 bf16 (4 VGPR)
typedef __attribute__((ext_vector_type(4))) float f32x4;    // MFMA accumulator

__device__ __forceinline__ unsigned short f2bf(float f) {   // RNE f32->bf16
    unsigned u = __float_as_uint(f);
    u += 0x7fffu + ((u >> 16) & 1u);
    return (unsigned short)(u >> 16);
}

// ---------------- prep: W [128x128 f32, k-major] -> Wf fragment-ordered bf16 ----------------
// Wf[((kc*8 + t)*64 + l)*8 + j] = bf16( W[ kc*32 + (l>>4)*4 + (j&3) + (j>>2)*16 ][ t*16 + (l&15) ] )
__global__ __launch_bounds__(256) void k_prep(const float* __restrict__ W,
                                              unsigned short* __restrict__ Wf) {
    int tid = blockIdx.x * 256 + threadIdx.x;   // 64 blocks x 256 = 16384
    int j  = tid & 7;
    int l  = (tid >> 3) & 63;
    int g  = tid >> 9;          // 0..31 = kc*8 + t
    int kc = g >> 3, t = g & 7;
    int k  = kc * 32 + ((l >> 4) * 4) + (j & 3) + ((j >> 2) * 16);
    int c  = t * 16 + (l & 15);
    Wf[tid] = f2bf(W[k * D + c]);
}

// ---------------- hybrid: slot placement (+degree) || MFMA GEMM (no LDS) ----------------
// even b, b/2 < gemmBlocks -> GEMM 64-row tile b/2 : y16[g][:] = bf16(seq[g] @ W)
// otherwise                -> placement: 4 edges/thread, slots[c*CAP + degP[c*16]++] = r
__global__ __launch_bounds__(256) void k_place_gemm(
        const int* __restrict__ row, const int* __restrict__ col,
        int* __restrict__ degP, int* __restrict__ slots,
        int* __restrict__ ovfCnt, int2* __restrict__ ovf, int E,
        int gemmBlocks,
        const float* __restrict__ seq, const unsigned short* __restrict__ Wf,
        unsigned short* __restrict__ y16, int n) {
    int b = (int)blockIdx.x;
    int half = b >> 1;
    bool isGemm = ((b & 1) == 0) && (half < gemmBlocks);

    if (!isGemm) {
        int pIdx = (b < 2 * gemmBlocks) ? half : (b - gemmBlocks);
        int t = pIdx * 256 + threadIdx.x;
        int e = 4 * t;
        if (e + 3 < E) {
            int4 c4 = *(const int4*)(col + e);
            int4 r4 = *(const int4*)(row + e);
            int p0 = atomicAdd(&degP[(size_t)c4.x * DPAD], 1);  // 4 independent chains,
            int p1 = atomicAdd(&degP[(size_t)c4.y * DPAD], 1);  // counters 64B apart
            int p2 = atomicAdd(&degP[(size_t)c4.z * DPAD], 1);
            int p3 = atomicAdd(&degP[(size_t)c4.w * DPAD], 1);
            if (p0 < CAP) slots[(size_t)c4.x * CAP + p0] = r4.x;
            else { int o = atomicAdd(ovfCnt, 1); if (o < OVFCAP) ovf[o] = make_int2(r4.x, c4.x); }
            if (p1 < CAP) slots[(size_t)c4.y * CAP + p1] = r4.y;
            else { int o = atomicAdd(ovfCnt, 1); if (o < OVFCAP) ovf[o] = make_int2(r4.y, c4.y); }
            if (p2 < CAP) slots[(size_t)c4.z * CAP + p2] = r4.z;
            else { int o = atomicAdd(ovfCnt, 1); if (o < OVFCAP) ovf[o] = make_int2(r4.z, c4.z); }
            if (p3 < CAP) slots[(size_t)c4.w * CAP + p3] = r4.w;
            else { int o = atomicAdd(ovfCnt, 1); if (o < OVFCAP) ovf[o] = make_int2(r4.w, c4.w); }
        } else {
            for (int j = 0; j < 4; ++j) {
                int ej = e + j;
                if (ej < E) {
                    int c = col[ej];
                    int r = row[ej];
                    int p = atomicAdd(&degP[(size_t)c * DPAD], 1);
                    if (p < CAP) slots[(size_t)c * CAP + p] = r;
                    else { int o = atomicAdd(ovfCnt, 1); if (o < OVFCAP) ovf[o] = make_int2(r, c); }
                }
            }
        }
        return;
    }

    // ---- GEMM path: 64-row tile, 4 waves x 16 rows, N=128 (8 n-tiles), K=128 (4 chunks) ----
    int w  = threadIdx.x >> 6;    // wave 0..3
    int l  = threadIdx.x & 63;
    int lr = l & 15;              // A-row / C-col within tile
    int lg = l >> 4;              // 0..3

    int row0 = half * 64;
    int m = row0 + w * 16 + lr;
    if (m >= n) m = n - 1;        // clamp (partial last tile; stores guarded below)
    const float* sp = seq + (size_t)m * D;

    f32x4 acc[8];
    #pragma unroll
    for (int t = 0; t < 8; ++t) acc[t] = (f32x4){0.f, 0.f, 0.f, 0.f};

    const short8* WfB = (const short8*)Wf;

    #pragma unroll
    for (int kc = 0; kc < 4; ++kc) {
        int kb = kc * 32 + lg * 4;
        float4 lo = *(const float4*)(sp + kb);        // k = kb..kb+3
        float4 hi = *(const float4*)(sp + kb + 16);   // k = kb+16..kb+19
        short8 a;
        a[0] = (short)f2bf(lo.x); a[1] = (short)f2bf(lo.y);
        a[2] = (short)f2bf(lo.z); a[3] = (short)f2bf(lo.w);
        a[4] = (short)f2bf(hi.x); a[5] = (short)f2bf(hi.y);
        a[6] = (short)f2bf(hi.z); a[7] = (short)f2bf(hi.w);
        #pragma unroll
        for (int t = 0; t < 8; ++t) {
            short8 bf = WfB[(kc * 8 + t) * 64 + l];   // coalesced 16B, L1/L2-hot
            acc[t] = __builtin_amdgcn_mfma_f32_16x16x32_bf16(a, bf, acc[t], 0, 0, 0);
        }
    }

    // C/D: col = lane&15 (= lr), row = (lane>>4)*4 + reg (= lg*4 + i)
    #pragma unroll
    for (int i = 0; i < 4; ++i) {
        int g = row0 + w * 16 + lg * 4 + i;
        if (g < n) {
            unsigned short* yp = y16 + (size_t)g * D + lr;
            #pragma unroll
            for (int t = 0; t < 8; ++t) yp[t * 16] = f2bf(acc[t][i]);
        }
    }
}

// ---------------- y16[i][:] *= rsqrt(deg[i]+1)   (fold source-side norm) ----------------
__global__ __launch_bounds__(256) void k_scale(unsigned short* __restrict__ y16,
                                               const int* __restrict__ degP, int n) {
    int tid = blockIdx.x * 256 + threadIdx.x;   // one per 8 bf16
    int total = n * (D / 8);
    if (tid >= total) return;
    int g = tid >> 4;                           // node (16 chunks per node)
    float di = rsqrtf((float)(degP[(size_t)g * DPAD] + 1));
    uint4 v = ((uint4*)y16)[tid];
    unsigned r0, r1, r2, r3;
    {
        float lo = __uint_as_float(v.x << 16) * di;
        float hi = __uint_as_float(v.x & 0xffff0000u) * di;
        r0 = (unsigned)f2bf(lo) | ((unsigned)f2bf(hi) << 16);
    }
    {
        float lo = __uint_as_float(v.y << 16) * di;
        float hi = __uint_as_float(v.y & 0xffff0000u) * di;
        r1 = (unsigned)f2bf(lo) | ((unsigned)f2bf(hi) << 16);
    }
    {
        float lo = __uint_as_float(v.z << 16) * di;
        float hi = __uint_as_float(v.z & 0xffff0000u) * di;
        r2 = (unsigned)f2bf(lo) | ((unsigned)f2bf(hi) << 16);
    }
    {
        float lo = __uint_as_float(v.w << 16) * di;
        float hi = __uint_as_float(v.w & 0xffff0000u) * di;
        r3 = (unsigned)f2bf(lo) | ((unsigned)f2bf(hi) << 16);
    }
    ((uint4*)y16)[tid] = make_uint4(r0, r1, r2, r3);
}

// ---------------- per-node gather-reduce + bias + PReLU ----------------
// y16 is pre-scaled by dinv:  out[c] = prelu( dc * ( y16s[c] + sum_e y16s[r_e] ) + b )
__global__ __launch_bounds__(256) void k_agg(
        const int* __restrict__ slots, const int* __restrict__ degP,
        const int* __restrict__ ovfCnt, const int2* __restrict__ ovf,
        const unsigned short* __restrict__ y16,
        const float* __restrict__ b, const float* __restrict__ pw,
        float* __restrict__ out, int n) {
    int wid = (blockIdx.x * 256 + threadIdx.x) >> 6;   // one wave per node
    if (wid >= n) return;
    int lane = threadIdx.x & 63;

    int cntf = degP[(size_t)wid * DPAD];
    int cnt = cntf < CAP ? cntf : CAP;
    float dc = rsqrtf((float)(cntf + 1));

    // self-loop term (y16s already includes this node's dinv); lane owns cols 2*lane..+1
    unsigned sv = *(const unsigned*)(y16 + (size_t)wid * D + 2 * lane);
    float ax0 = __uint_as_float(sv << 16);
    float ay0 = __uint_as_float(sv & 0xffff0000u);
    float ax1 = 0.f, ay1 = 0.f, ax2 = 0.f, ay2 = 0.f, ax3 = 0.f, ay3 = 0.f;
    float ax4 = 0.f, ay4 = 0.f, ax5 = 0.f, ay5 = 0.f, ax6 = 0.f, ay6 = 0.f;
    float ax7 = 0.f, ay7 = 0.f;

    int my = (lane < cnt) ? slots[(size_t)wid * CAP + lane] : 0;

    int k = 0;
    for (; k + 7 < cnt; k += 8) {   // 8 independent gather chains in flight
        int r0 = __shfl(my, k);
        int r1 = __shfl(my, k + 1);
        int r2 = __shfl(my, k + 2);
        int r3 = __shfl(my, k + 3);
        int r4 = __shfl(my, k + 4);
        int r5 = __shfl(my, k + 5);
        int r6 = __shfl(my, k + 6);
        int r7 = __shfl(my, k + 7);
        unsigned v0 = *(const unsigned*)(y16 + (size_t)r0 * D + 2 * lane);
        unsigned v1 = *(const unsigned*)(y16 + (size_t)r1 * D + 2 * lane);
        unsigned v2 = *(const unsigned*)(y16 + (size_t)r2 * D + 2 * lane);
        unsigned v3 = *(const unsigned*)(y16 + (size_t)r3 * D + 2 * lane);
        unsigned v4 = *(const unsigned*)(y16 + (size_t)r4 * D + 2 * lane);
        unsigned v5 = *(const unsigned*)(y16 + (size_t)r5 * D + 2 * lane);
        unsigned v6 = *(const unsigned*)(y16 + (size_t)r6 * D + 2 * lane);
        unsigned v7 = *(const unsigned*)(y16 + (size_t)r7 * D + 2 * lane);
        ax0 += __uint_as_float(v0 << 16); ay0 += __uint_as_float(v0 & 0xffff0000u);
        ax1 += __uint_as_float(v1 << 16); ay1 += __uint_as_float(v1 & 0xffff0000u);
        ax2 += __uint_as_float(v2 << 16); ay2 += __uint_as_float(v2 & 0xffff0000u);
        ax3 += __uint_as_float(v3 << 16); ay3 += __uint_as_float(v3 & 0xffff0000u);
        ax4 += __uint_as_float(v4 << 16); ay4 += __uint_as_float(v4 & 0xffff0000u);
        ax5 += __uint_as_float(v5 << 16); ay5 += __uint_as_float(v5 & 0xffff0000u);
        ax6 += __uint_as_float(v6 << 16); ay6 += __uint_as_float(v6 & 0xffff0000u);
        ax7 += __uint_as_float(v7 << 16); ay7 += __uint_as_float(v7 & 0xffff0000u);
    }
    for (; k < cnt; ++k) {
        int r = __shfl(my, k);
        unsigned v = *(const unsigned*)(y16 + (size_t)r * D + 2 * lane);
        ax0 += __uint_as_float(v << 16);
        ay0 += __uint_as_float(v & 0xffff0000u);
    }

    if (cntf > CAP) {   // overflow drain (never taken for this input; correctness net)
        int m = *ovfCnt; if (m > OVFCAP) m = OVFCAP;
        for (int j = 0; j < m; ++j) {
            int2 pr = ovf[j];
            if (pr.y == wid) {
                unsigned v = *(const unsigned*)(y16 + (size_t)pr.x * D + 2 * lane);
                ax0 += __uint_as_float(v << 16);
                ay0 += __uint_as_float(v & 0xffff0000u);
            }
        }
    }

    float sx = ((ax0 + ax1) + (ax2 + ax3)) + ((ax4 + ax5) + (ax6 + ax7));
    float sy = ((ay0 + ay1) + (ay2 + ay3)) + ((ay4 + ay5) + (ay6 + ay7));

    float2 bb = *(const float2*)(b + 2 * lane);
    float p = pw[0];
    float vx = sx * dc + bb.x;
    float vy = sy * dc + bb.y;
    vx = vx > 0.f ? vx : p * vx;
    vy = vy > 0.f ? vy : p * vy;
    *(float2*)(out + (size_t)wid * D + 2 * lane) = make_float2(vx, vy);
}

extern "C" void kernel_launch(void* const* d_in, const int* in_sizes, int n_in,
                              void* d_out, int out_size, void* d_ws, size_t ws_size,
                              hipStream_t stream) {
    const float* seq = (const float*)d_in[0];
    const int*   ei  = (const int*)d_in[1];   // [2, E]: row = ei, col = ei + E
    const float* W   = (const float*)d_in[2];
    const float* b   = (const float*)d_in[3];
    const float* pw  = (const float*)d_in[4];
    int n = in_sizes[0] / D;
    int E = in_sizes[1] / 2;

    float* out = (float*)d_out;

    // workspace layout (256B-aligned chunks): ~26.4 MB
    auto align = [](size_t x) { return (x + 255) & ~(size_t)255; };
    char* p = (char*)d_ws;
    unsigned short* y16 = (unsigned short*)p; p += align((size_t)n * D * sizeof(unsigned short));
    int*  degP   = (int*)p;   size_t degBytes = align((size_t)n * DPAD * sizeof(int)); p += degBytes;
    int*  ovfCnt = (int*)p;   p += 256;
    int2* ovf    = (int2*)p;  p += align((size_t)OVFCAP * sizeof(int2));
    int*  slots  = (int*)p;   p += align((size_t)n * CAP * sizeof(int));
    unsigned short* Wf = (unsigned short*)p; p += align((size_t)D * D * sizeof(unsigned short));

    // zero degP + ovfCnt in one memset (contiguous)
    hipMemsetAsync(degP, 0, degBytes + 256, stream);
    k_prep<<<64, 256, 0, stream>>>(W, Wf);

    int GB = (n + 63) / 64;          // 782 GEMM tiles (64 rows)
    int PB = (E + 1023) / 1024;      // 782 placement blocks (4 edges/thread)
    k_place_gemm<<<GB + PB, 256, 0, stream>>>(
        ei, ei + E, degP, slots, ovfCnt, ovf, E, GB, seq, Wf, y16, n);

    int scaleTotal = n * (D / 8);
    k_scale<<<(scaleTotal + 255) / 256, 256, 0, stream>>>(y16, degP, n);

    k_agg<<<(unsigned)(((long long)n * 64 + 255) / 256), 256, 0, stream>>>(
        slots, degP, ovfCnt, ovf, y16, b, pw, out, n);
}